// Round 11
// baseline (395.160 us; speedup 1.0000x reference)
//
#include <hip/hip_runtime.h>

#define N_SEQ 16384
#define LSEQ  512
#define VOCAB 32000
#define ES    32
#define HS    64
#define LDH   72    // padded f16 stride per m-row in LDS

#define SC_RZ (-1.4426950408889634f)   // -log2(e): folded into r,z weights
#define SC_N  (-2.8853900817779268f)   // -2*log2(e): folded into n weights

typedef _Float16 v8h __attribute__((ext_vector_type(8)));
typedef float    v4f __attribute__((ext_vector_type(4)));

// ---------------- K1 (fused prep): lengths+hist | emb->f16 | weight packs ---
#define NLB (N_SEQ / 4)            // 4096 blocks: lengths
#define NEB (VOCAB * ES / 256)     // 4000 blocks: emb convert
__global__ __launch_bounds__(256) void k_prep(const int* __restrict__ x,
                                              const float* __restrict__ emb,
                                              const float* __restrict__ whh,
                                              const float* __restrict__ wih,
                                              int* __restrict__ len,
                                              int* __restrict__ hist,
                                              _Float16* __restrict__ ef,
                                              _Float16* __restrict__ wpk,
                                              _Float16* __restrict__ wpe){
  int b = blockIdx.x;
  if (b < NLB){                               // ---- lengths + histogram
    int wid  = (b * 256 + threadIdx.x) >> 6;
    int lane = threadIdx.x & 63;
    const int* xr = x + (size_t)wid * LSEQ;
    int cnt = 0;
    #pragma unroll
    for (int j = 0; j < 8; ++j) cnt += (xr[lane + 64*j] != 0) ? 1 : 0;
    #pragma unroll
    for (int o = 32; o; o >>= 1) cnt += __shfl_down(cnt, o, 64);
    if (lane == 0){ len[wid] = cnt; atomicAdd(&hist[cnt], 1); }
  } else if (b < NLB + NEB){                  // ---- embedding f32 -> f16
    int i = (b - NLB) * 256 + threadIdx.x;
    ef[i] = (_Float16)emb[i];
  } else if (b < NLB + NEB + 6){              // ---- pack w_hh (K=64: 2 frags)
    int tid = (b - NLB - NEB) * 256 + threadIdx.x;
    int f = tid >> 6, l = tid & 63;
    int jt = f >> 1, kf = f & 1;
    float sc = (jt < 8) ? SC_RZ : SC_N;       // exp2-arg scale folded in
    #pragma unroll
    for (int i = 0; i < 8; ++i){
      int row = jt * 16 + (l & 15);
      int col = kf * 32 + (l >> 4) * 8 + i;
      wpk[(size_t)tid * 8 + i] = (_Float16)(sc * whh[row * HS + col]);
    }
  } else {                                    // ---- pack w_ih (K=32: 1 frag)
    int tid = (b - NLB - NEB - 6) * 256 + threadIdx.x;
    int tile = tid >> 6, l = tid & 63;
    float sc = ((tile >> 2) < 2) ? SC_RZ : SC_N;
    #pragma unroll
    for (int i = 0; i < 8; ++i){
      int row = tile * 16 + (l & 15);
      int col = (l >> 4) * 8 + i;
      wpe[(size_t)tid * 8 + i] = (_Float16)(sc * wih[row * ES + col]);
    }
  }
}

// ---------------- K2: exclusive scan of hist[0..512] -> offs ----------------
__global__ __launch_bounds__(1024) void k_scan(const int* __restrict__ hist,
                                               int* __restrict__ offs){
  __shared__ int buf[1024];
  int i = threadIdx.x;
  buf[i] = (i < 513) ? hist[i] : 0;
  __syncthreads();
  for (int d = 1; d < 1024; d <<= 1){
    int v = (i >= d) ? buf[i - d] : 0;
    __syncthreads();
    buf[i] += v;
    __syncthreads();
  }
  if (i < 513) offs[i] = (i == 0) ? 0 : buf[i - 1];
}

// ---------------- K3: scatter seq ids sorted (ascending) by length ----------
__global__ __launch_bounds__(256) void k_scatter(const int* __restrict__ len,
                                                 int* __restrict__ offs,
                                                 int* __restrict__ perm){
  int i = blockIdx.x * 256 + threadIdx.x;
  int l = len[i];
  int pos = atomicAdd(&offs[l], 1);
  perm[pos] = i;
}

// ---------------- K4: recurrence, equal-total chained blocks ----------------
// R8 per-step structure (4-way u-split, fused e-MFMA prefetch, folded exp2
// scales, select-free main loop) with a new schedule: 512 blocks, block b
// processes group (1023-b) then group b sequentially. Sorted lengths are
// ~uniform, so every block's total steps ~= 512: all 512 blocks co-resident
// from t=0 (2 blocks/CU), all finish together -> no endgame occupancy decay
// (R8's makespan was 512 x T(4)=1220 because long blocks shared their SIMDs
// with short-lived siblings; here w=2 constant, T(2,s=300) ~ 650-900).
__global__ __launch_bounds__(256, 2) void k_gru(
    const int* __restrict__ x, const _Float16* __restrict__ ef,
    const _Float16* __restrict__ wpk, const _Float16* __restrict__ wpe,
    const float* __restrict__ bih, const float* __restrict__ bhh,
    const int* __restrict__ perm, const int* __restrict__ len,
    float* __restrict__ out)
{
  __shared__ __align__(16) _Float16 hb[2][16 * LDH];
  int qt   = threadIdx.x >> 6;
  int lane = threadIdx.x & 63;
  int q = lane >> 4, c = lane & 15;
  int uu = qt*16 + c;

  // resident B fragments (shared across both phases)
  v8h bfh[3][2], bfe[3];
  #pragma unroll
  for (int g = 0; g < 3; ++g){
    int tile = g*4 + qt;
    #pragma unroll
    for (int kf = 0; kf < 2; ++kf)
      bfh[g][kf] = *(const v8h*)(wpk + ((size_t)(tile*2 + kf)*64 + lane)*8);
    bfe[g] = *(const v8h*)(wpe + ((size_t)tile*64 + lane)*8);
  }

  float br  = SC_RZ * (bih[uu]      + bhh[uu]);
  float bz  = SC_RZ * (bih[HS + uu] + bhh[HS + uu]);
  float ben = SC_N  *  bih[2*HS + uu];
  float bhn = SC_N  *  bhh[2*HS + uu];
  v4f brq  = {br, br, br, br};
  v4f bzq  = {bz, bz, bz, bz};
  v4f benq = {ben, ben, ben, ben};
  v4f bhnq = {bhn, bhn, bhn, bhn};

  for (int ph = 0; ph < 2; ++ph){
    int grp = ph ? (int)blockIdx.x : (1023 - (int)blockIdx.x);

    int sq[4], ln[4];
    #pragma unroll
    for (int r = 0; r < 4; ++r){
      int s = perm[grp * 16 + q*4 + r];
      sq[r] = s;
      ln[r] = len[s];
    }

    float h[4];
    #pragma unroll
    for (int r = 0; r < 4; ++r) h[r] = 0.f;

    for (int i = threadIdx.x; i < 16*LDH; i += 256) hb[0][i] = (_Float16)0.f;
    __syncthreads();

    int tmax = max(max(ln[0], ln[1]), max(ln[2], ln[3]));
    tmax = max(tmax, __shfl_xor(tmax, 16, 64));
    tmax = max(tmax, __shfl_xor(tmax, 32, 64));
    int tmin = min(min(ln[0], ln[1]), min(ln[2], ln[3]));
    tmin = min(tmin, __shfl_xor(tmin, 16, 64));
    tmin = min(tmin, __shfl_xor(tmin, 32, 64));

    const int* xr = x + (size_t)perm[grp * 16 + c] * LSEQ;  // A-row m=c tokens

    v8h aec, aen;
    int tk1, tk2;
    v4f pra, prb, pza, pzb, dea, deb;   // e-partials: r, z, n (ping/pong)
    {
      int tk0 = xr[0];
      aec = *(const v8h*)(ef + (size_t)tk0 * ES + q*8);
      tk1 = xr[1];
      pra = __builtin_amdgcn_mfma_f32_16x16x32_f16(aec, bfe[0], brq,  0,0,0);
      pza = __builtin_amdgcn_mfma_f32_16x16x32_f16(aec, bfe[1], bzq,  0,0,0);
      dea = __builtin_amdgcn_mfma_f32_16x16x32_f16(aec, bfe[2], benq, 0,0,0);
    }

    #define GRU_STEP(FREEZE, AEN, PRR, PRZ, DEN, PRRn, PRZn, DENn, TKN_, TKNN_, RB, WB) \
    {                                                                          \
      AEN = *(const v8h*)(ef + (size_t)TKN_ * ES + q*8);   /* emb frag t+1 */  \
      int t2 = min(t + 2, LSEQ - 1);                                           \
      TKNN_ = xr[t2];                                      /* token t+2 */     \
      v8h a0 = *(const v8h*)(&hb[RB][c*LDH + q*8]);                            \
      v8h a1 = *(const v8h*)(&hb[RB][c*LDH + 32 + q*8]);                       \
      v4f zr  = __builtin_amdgcn_mfma_f32_16x16x32_f16(a1, bfh[0][1], PRR, 0,0,0);\
      v4f Dr  = __builtin_amdgcn_mfma_f32_16x16x32_f16(a0, bfh[0][0], zr,  0,0,0);\
      v4f zz  = __builtin_amdgcn_mfma_f32_16x16x32_f16(a1, bfh[1][1], PRZ, 0,0,0);\
      v4f Dz  = __builtin_amdgcn_mfma_f32_16x16x32_f16(a0, bfh[1][0], zz,  0,0,0);\
      v4f zh  = __builtin_amdgcn_mfma_f32_16x16x32_f16(a1, bfh[2][1], bhnq,0,0,0);\
      v4f Dhn = __builtin_amdgcn_mfma_f32_16x16x32_f16(a0, bfh[2][0], zh,  0,0,0);\
      _Pragma("unroll")                                                        \
      for (int r = 0; r < 4; ++r){                                             \
        float rg   = __builtin_amdgcn_rcpf(1.f + __builtin_amdgcn_exp2f(Dr[r]));\
        float zg   = __builtin_amdgcn_rcpf(1.f + __builtin_amdgcn_exp2f(Dz[r]));\
        float te   = __builtin_amdgcn_exp2f(DEN[r] + rg * Dhn[r]);             \
        float ng   = fmaf(2.f, __builtin_amdgcn_rcpf(1.f + te), -1.f);         \
        float hnew = ng + zg * (h[r] - ng);                                    \
        h[r]       = (FREEZE && t >= ln[r]) ? h[r] : hnew;                     \
      }                                                                        \
      PRRn = __builtin_amdgcn_mfma_f32_16x16x32_f16(AEN, bfe[0], brq,  0,0,0); \
      PRZn = __builtin_amdgcn_mfma_f32_16x16x32_f16(AEN, bfe[1], bzq,  0,0,0); \
      DENn = __builtin_amdgcn_mfma_f32_16x16x32_f16(AEN, bfe[2], benq, 0,0,0); \
      _Pragma("unroll")                                                        \
      for (int r = 0; r < 4; ++r)                                              \
        hb[WB][(q*4 + r)*LDH + uu] = (_Float16)h[r];                           \
      __syncthreads();                                                         \
    }

    int t = 0;
    for (; t + 1 < tmin; ){   // no-freeze main loop
      GRU_STEP(0, aen, pra, pza, dea, prb, pzb, deb, tk1, tk2, 0, 1); ++t;
      GRU_STEP(0, aec, prb, pzb, deb, pra, pza, dea, tk2, tk1, 1, 0); ++t;
    }
    for (; t + 1 < tmax; ){   // tail pairs with freeze
      GRU_STEP(1, aen, pra, pza, dea, prb, pzb, deb, tk1, tk2, 0, 1); ++t;
      GRU_STEP(1, aec, prb, pzb, deb, pra, pza, dea, tk2, tk1, 1, 0); ++t;
    }
    if (t < tmax){
      GRU_STEP(1, aen, pra, pza, dea, prb, pzb, deb, tk1, tk2, 0, 1); ++t;
    }
    #undef GRU_STEP

    #pragma unroll
    for (int r = 0; r < 4; ++r)
      out[(size_t)sq[r] * HS + uu] = h[r];

    __syncthreads();   // phase boundary: protect hb reuse
  }
}

extern "C" void kernel_launch(void* const* d_in, const int* in_sizes, int n_in,
                              void* d_out, int out_size, void* d_ws, size_t ws_size,
                              hipStream_t stream){
  const int*   x   = (const int*)  d_in[0];
  const float* emb = (const float*)d_in[1];
  const float* wih = (const float*)d_in[2];
  const float* whh = (const float*)d_in[3];
  const float* bih = (const float*)d_in[4];
  const float* bhh = (const float*)d_in[5];
  float* out = (float*)d_out;

  char* ws = (char*)d_ws;
  size_t off = 0;
  _Float16* ef  = (_Float16*)(ws + off);  off += (size_t)VOCAB * ES * sizeof(_Float16);
  _Float16* wpk = (_Float16*)(ws + off);  off += (size_t)24 * 64 * 8 * sizeof(_Float16);
  _Float16* wpe = (_Float16*)(ws + off);  off += (size_t)12 * 64 * 8 * sizeof(_Float16);
  off = (off + 255) & ~(size_t)255;
  int* len  = (int*)(ws + off);           off += (size_t)N_SEQ * sizeof(int);
  int* perm = (int*)(ws + off);           off += (size_t)N_SEQ * sizeof(int);
  int* hist = (int*)(ws + off);           off += 513 * sizeof(int);
  off = (off + 255) & ~(size_t)255;
  int* offs = (int*)(ws + off);           off += 513 * sizeof(int);

  hipMemsetAsync(hist, 0, 513 * sizeof(int), stream);
  k_prep   <<<NLB + NEB + 9, 256, 0, stream>>>(x, emb, whh, wih, len, hist, ef, wpk, wpe);
  k_scan   <<<1,            1024, 0, stream>>>(hist, offs);
  k_scatter<<<N_SEQ / 256,   256, 0, stream>>>(len, offs, perm);
  k_gru    <<<512,           256, 0, stream>>>(x, ef, wpk, wpe, bih, bhh, perm, len, out);
}

// Round 12
// 325.788 us; speedup vs baseline: 1.2129x; 1.2129x over previous
//
#include <hip/hip_runtime.h>

#define N_SEQ 16384
#define LSEQ  512
#define VOCAB 32000
#define ES    32
#define HS    64
#define LDH   72    // padded f16 stride per m-row in LDS

#define SC_RZ (-1.4426950408889634f)   // -log2(e): folded into r,z weights
#define SC_N  (-2.8853900817779268f)   // -2*log2(e): folded into n weights

typedef _Float16 v8h __attribute__((ext_vector_type(8)));
typedef float    v4f __attribute__((ext_vector_type(4)));

// ---------------- K1 (fused prep): lengths+hist | emb->f16 | weight packs ---
#define NLB (N_SEQ / 4)            // 4096 blocks: lengths
#define NEB (VOCAB * ES / 256)     // 4000 blocks: emb convert
__global__ __launch_bounds__(256) void k_prep(const int* __restrict__ x,
                                              const float* __restrict__ emb,
                                              const float* __restrict__ whh,
                                              const float* __restrict__ wih,
                                              int* __restrict__ len,
                                              int* __restrict__ hist,
                                              _Float16* __restrict__ ef,
                                              _Float16* __restrict__ wpk,
                                              _Float16* __restrict__ wpe){
  int b = blockIdx.x;
  if (b < NLB){                               // ---- lengths + histogram
    int wid  = (b * 256 + threadIdx.x) >> 6;
    int lane = threadIdx.x & 63;
    const int* xr = x + (size_t)wid * LSEQ;
    int cnt = 0;
    #pragma unroll
    for (int j = 0; j < 8; ++j) cnt += (xr[lane + 64*j] != 0) ? 1 : 0;
    #pragma unroll
    for (int o = 32; o; o >>= 1) cnt += __shfl_down(cnt, o, 64);
    if (lane == 0){ len[wid] = cnt; atomicAdd(&hist[cnt], 1); }
  } else if (b < NLB + NEB){                  // ---- embedding f32 -> f16
    int i = (b - NLB) * 256 + threadIdx.x;
    ef[i] = (_Float16)emb[i];
  } else if (b < NLB + NEB + 6){              // ---- pack w_hh (K=64: 2 frags)
    int tid = (b - NLB - NEB) * 256 + threadIdx.x;
    int f = tid >> 6, l = tid & 63;
    int jt = f >> 1, kf = f & 1;
    float sc = (jt < 8) ? SC_RZ : SC_N;       // exp2-arg scale folded in
    #pragma unroll
    for (int i = 0; i < 8; ++i){
      int row = jt * 16 + (l & 15);
      int col = kf * 32 + (l >> 4) * 8 + i;
      wpk[(size_t)tid * 8 + i] = (_Float16)(sc * whh[row * HS + col]);
    }
  } else {                                    // ---- pack w_ih (K=32: 1 frag)
    int tid = (b - NLB - NEB - 6) * 256 + threadIdx.x;
    int tile = tid >> 6, l = tid & 63;
    float sc = ((tile >> 2) < 2) ? SC_RZ : SC_N;
    #pragma unroll
    for (int i = 0; i < 8; ++i){
      int row = tile * 16 + (l & 15);
      int col = (l >> 4) * 8 + i;
      wpe[(size_t)tid * 8 + i] = (_Float16)(sc * wih[row * ES + col]);
    }
  }
}

// ---------------- K2: exclusive scan of hist[0..512] -> offs ----------------
__global__ __launch_bounds__(1024) void k_scan(const int* __restrict__ hist,
                                               int* __restrict__ offs){
  __shared__ int buf[1024];
  int i = threadIdx.x;
  buf[i] = (i < 513) ? hist[i] : 0;
  __syncthreads();
  for (int d = 1; d < 1024; d <<= 1){
    int v = (i >= d) ? buf[i - d] : 0;
    __syncthreads();
    buf[i] += v;
    __syncthreads();
  }
  if (i < 513) offs[i] = (i == 0) ? 0 : buf[i - 1];
}

// ---------------- K3: scatter seq ids sorted (ascending) by length ----------
__global__ __launch_bounds__(256) void k_scatter(const int* __restrict__ len,
                                                 int* __restrict__ offs,
                                                 int* __restrict__ perm){
  int i = blockIdx.x * 256 + threadIdx.x;
  int l = len[i];
  int pos = atomicAdd(&offs[l], 1);
  perm[pos] = i;
}

// ---------------- K4: recurrence (R8 config + phase stagger) ----------------
// R8 structure restored: 1024 blocks (4/CU, the measured optimum of the
// co-residency ladder: T(4)=1223 vs T(2)=1540 cyc/step), serpentine balance,
// 4-way u-split, fused e-MFMA prefetch, folded exp2 scales, select-free main
// loop, __syncthreads per step. New: (a) same-CU blocks (blockIdx = k+256m)
// start phase-staggered by m*~320 cyc (s_sleep) so their per-step barriers
// interleave instead of colliding — un-phase-locking the 4 waves/SIMD whose
// simultaneous serial chains (ds_read->MFMA->trans) are the ~19% gap between
// measured T=1223 and the 992-cyc VALU-pipe floor; (b) h[r] written to LDS
// immediately after computation, overlapping ds ops with the next r's trans.
__global__ __launch_bounds__(256, 4) void k_gru(
    const int* __restrict__ x, const _Float16* __restrict__ ef,
    const _Float16* __restrict__ wpk, const _Float16* __restrict__ wpe,
    const float* __restrict__ bih, const float* __restrict__ bhh,
    const int* __restrict__ perm, const int* __restrict__ len,
    float* __restrict__ out)
{
  __shared__ __align__(16) _Float16 hb[2][16 * LDH];
  int qt   = threadIdx.x >> 6;
  int w = blockIdx.x >> 8, cq = blockIdx.x & 255;
  int rank = w * 256 + ((w & 1) ? (255 - cq) : cq);   // 0 = longest
  int grp  = 1023 - rank;                             // ascending-sorted index
  int lane = threadIdx.x & 63;
  int q = lane >> 4, c = lane & 15;
  int uu = qt*16 + c;

  v8h bfh[3][2], bfe[3];
  #pragma unroll
  for (int g = 0; g < 3; ++g){
    int tile = g*4 + qt;
    #pragma unroll
    for (int kf = 0; kf < 2; ++kf)
      bfh[g][kf] = *(const v8h*)(wpk + ((size_t)(tile*2 + kf)*64 + lane)*8);
    bfe[g] = *(const v8h*)(wpe + ((size_t)tile*64 + lane)*8);
  }

  int sq[4], ln[4];
  #pragma unroll
  for (int r = 0; r < 4; ++r){
    int s = perm[grp * 16 + q*4 + r];
    sq[r] = s;
    ln[r] = len[s];
  }
  float br  = SC_RZ * (bih[uu]      + bhh[uu]);
  float bz  = SC_RZ * (bih[HS + uu] + bhh[HS + uu]);
  float ben = SC_N  *  bih[2*HS + uu];
  float bhn = SC_N  *  bhh[2*HS + uu];
  v4f brq  = {br, br, br, br};
  v4f bzq  = {bz, bz, bz, bz};
  v4f benq = {ben, ben, ben, ben};
  v4f bhnq = {bhn, bhn, bhn, bhn};

  float h[4];
  #pragma unroll
  for (int r = 0; r < 4; ++r) h[r] = 0.f;

  for (int i = threadIdx.x; i < 16*LDH; i += 256) hb[0][i] = (_Float16)0.f;

  // phase stagger: same-CU siblings are blockIdx k, k+256, k+512, k+768 under
  // round-robin dispatch; offset their step rhythm by ~quarter periods.
  for (int i = 0; i < w; ++i) __builtin_amdgcn_s_sleep(5);   // w*320 cyc
  __syncthreads();

  int tmax = max(max(ln[0], ln[1]), max(ln[2], ln[3]));
  tmax = max(tmax, __shfl_xor(tmax, 16, 64));
  tmax = max(tmax, __shfl_xor(tmax, 32, 64));
  int tmin = min(min(ln[0], ln[1]), min(ln[2], ln[3]));
  tmin = min(tmin, __shfl_xor(tmin, 16, 64));
  tmin = min(tmin, __shfl_xor(tmin, 32, 64));

  const int* xr = x + (size_t)perm[grp * 16 + c] * LSEQ;  // A-row m=c tokens

  v8h aec, aen;
  int tk1, tk2;
  v4f pra, prb, pza, pzb, dea, deb;   // e-partials: r, z, n (ping/pong)
  {
    int tk0 = xr[0];
    aec = *(const v8h*)(ef + (size_t)tk0 * ES + q*8);
    tk1 = xr[1];
    pra = __builtin_amdgcn_mfma_f32_16x16x32_f16(aec, bfe[0], brq,  0,0,0);
    pza = __builtin_amdgcn_mfma_f32_16x16x32_f16(aec, bfe[1], bzq,  0,0,0);
    dea = __builtin_amdgcn_mfma_f32_16x16x32_f16(aec, bfe[2], benq, 0,0,0);
  }

  // FREEZE is compile-time 0/1: main loop (0) skips the per-row length select.
  #define GRU_STEP(FREEZE, AEN, PRR, PRZ, DEN, PRRn, PRZn, DENn, TKN_, TKNN_, RB, WB) \
  {                                                                            \
    AEN = *(const v8h*)(ef + (size_t)TKN_ * ES + q*8);   /* emb frag t+1 */    \
    int t2 = min(t + 2, LSEQ - 1);                                             \
    TKNN_ = xr[t2];                                      /* token t+2 */       \
    v8h a0 = *(const v8h*)(&hb[RB][c*LDH + q*8]);                              \
    v8h a1 = *(const v8h*)(&hb[RB][c*LDH + 32 + q*8]);                         \
    v4f zr  = __builtin_amdgcn_mfma_f32_16x16x32_f16(a1, bfh[0][1], PRR, 0,0,0);\
    v4f Dr  = __builtin_amdgcn_mfma_f32_16x16x32_f16(a0, bfh[0][0], zr,  0,0,0);\
    v4f zz  = __builtin_amdgcn_mfma_f32_16x16x32_f16(a1, bfh[1][1], PRZ, 0,0,0);\
    v4f Dz  = __builtin_amdgcn_mfma_f32_16x16x32_f16(a0, bfh[1][0], zz,  0,0,0);\
    v4f zh  = __builtin_amdgcn_mfma_f32_16x16x32_f16(a1, bfh[2][1], bhnq,0,0,0);\
    v4f Dhn = __builtin_amdgcn_mfma_f32_16x16x32_f16(a0, bfh[2][0], zh,  0,0,0);\
    _Pragma("unroll")                                                          \
    for (int r = 0; r < 4; ++r){                                               \
      float rg   = __builtin_amdgcn_rcpf(1.f + __builtin_amdgcn_exp2f(Dr[r])); \
      float zg   = __builtin_amdgcn_rcpf(1.f + __builtin_amdgcn_exp2f(Dz[r])); \
      float te   = __builtin_amdgcn_exp2f(DEN[r] + rg * Dhn[r]);               \
      float ng   = fmaf(2.f, __builtin_amdgcn_rcpf(1.f + te), -1.f);           \
      float hnew = ng + zg * (h[r] - ng);                                      \
      h[r]       = (FREEZE && t >= ln[r]) ? h[r] : hnew;                       \
      hb[WB][(q*4 + r)*LDH + uu] = (_Float16)h[r];   /* inline ds overlap */   \
    }                                                                          \
    PRRn = __builtin_amdgcn_mfma_f32_16x16x32_f16(AEN, bfe[0], brq,  0,0,0);   \
    PRZn = __builtin_amdgcn_mfma_f32_16x16x32_f16(AEN, bfe[1], bzq,  0,0,0);   \
    DENn = __builtin_amdgcn_mfma_f32_16x16x32_f16(AEN, bfe[2], benq, 0,0,0);   \
    __syncthreads();                                                           \
  }

  int t = 0;
  for (; t + 1 < tmin; ){   // no-freeze main loop (t and t+1 both < all ln)
    GRU_STEP(0, aen, pra, pza, dea, prb, pzb, deb, tk1, tk2, 0, 1); ++t;
    GRU_STEP(0, aec, prb, pzb, deb, pra, pza, dea, tk2, tk1, 1, 0); ++t;
  }
  for (; t + 1 < tmax; ){   // tail pairs with freeze (parity preserved)
    GRU_STEP(1, aen, pra, pza, dea, prb, pzb, deb, tk1, tk2, 0, 1); ++t;
    GRU_STEP(1, aec, prb, pzb, deb, pra, pza, dea, tk2, tk1, 1, 0); ++t;
  }
  if (t < tmax){
    GRU_STEP(1, aen, pra, pza, dea, prb, pzb, deb, tk1, tk2, 0, 1); ++t;
  }
  #undef GRU_STEP

  #pragma unroll
  for (int r = 0; r < 4; ++r)
    out[(size_t)sq[r] * HS + uu] = h[r];
}

extern "C" void kernel_launch(void* const* d_in, const int* in_sizes, int n_in,
                              void* d_out, int out_size, void* d_ws, size_t ws_size,
                              hipStream_t stream){
  const int*   x   = (const int*)  d_in[0];
  const float* emb = (const float*)d_in[1];
  const float* wih = (const float*)d_in[2];
  const float* whh = (const float*)d_in[3];
  const float* bih = (const float*)d_in[4];
  const float* bhh = (const float*)d_in[5];
  float* out = (float*)d_out;

  char* ws = (char*)d_ws;
  size_t off = 0;
  _Float16* ef  = (_Float16*)(ws + off);  off += (size_t)VOCAB * ES * sizeof(_Float16);
  _Float16* wpk = (_Float16*)(ws + off);  off += (size_t)24 * 64 * 8 * sizeof(_Float16);
  _Float16* wpe = (_Float16*)(ws + off);  off += (size_t)12 * 64 * 8 * sizeof(_Float16);
  off = (off + 255) & ~(size_t)255;
  int* len  = (int*)(ws + off);           off += (size_t)N_SEQ * sizeof(int);
  int* perm = (int*)(ws + off);           off += (size_t)N_SEQ * sizeof(int);
  int* hist = (int*)(ws + off);           off += 513 * sizeof(int);
  off = (off + 255) & ~(size_t)255;
  int* offs = (int*)(ws + off);           off += 513 * sizeof(int);

  hipMemsetAsync(hist, 0, 513 * sizeof(int), stream);
  k_prep   <<<NLB + NEB + 9, 256, 0, stream>>>(x, emb, whh, wih, len, hist, ef, wpk, wpe);
  k_scan   <<<1,            1024, 0, stream>>>(hist, offs);
  k_scatter<<<N_SEQ / 256,   256, 0, stream>>>(len, offs, perm);
  k_gru    <<<N_SEQ / 16,    256, 0, stream>>>(x, ef, wpk, wpe, bih, bhh, perm, len, out);
}

// Round 13
// 310.253 us; speedup vs baseline: 1.2737x; 1.0501x over previous
//
#include <hip/hip_runtime.h>

#define N_SEQ 16384
#define LSEQ  512
#define VOCAB 32000
#define ES    32
#define HS    64
#define LDH   72    // padded f16 stride per m-row in LDS

#define SC_RZ (-1.4426950408889634f)   // -log2(e): folded into r,z weights
#define SC_N  (-2.8853900817779268f)   // -2*log2(e): folded into n weights

typedef _Float16 v8h __attribute__((ext_vector_type(8)));
typedef float    v4f __attribute__((ext_vector_type(4)));

// ---------------- K1 (fused prep): lengths | emb->f16 | weight packs --------
#define NLB (N_SEQ / 256)          // 64 blocks: binary-search lengths
#define NEB (VOCAB * ES / 256)     // 4000 blocks: emb convert
__global__ __launch_bounds__(256) void k_prep(const int* __restrict__ x,
                                              const float* __restrict__ emb,
                                              const float* __restrict__ whh,
                                              const float* __restrict__ wih,
                                              int* __restrict__ len,
                                              int* __restrict__ hist,
                                              _Float16* __restrict__ ef,
                                              _Float16* __restrict__ wpk,
                                              _Float16* __restrict__ wpe){
  int b = blockIdx.x;
  if (b < NLB){                               // ---- lengths: binary search
    // rows are token-prefix + zero-pad: (x[t]!=0) is true exactly for t<len
    int row = b * 256 + threadIdx.x;
    const int* xr = x + (size_t)row * LSEQ;
    int lo = 0, hi = LSEQ;
    while (lo < hi){ int mid = (lo + hi) >> 1; if (xr[mid] != 0) lo = mid + 1; else hi = mid; }
    len[row] = lo;
    atomicAdd(&hist[lo], 1);
  } else if (b < NLB + NEB){                  // ---- embedding f32 -> f16
    int i = (b - NLB) * 256 + threadIdx.x;
    ef[i] = (_Float16)emb[i];
  } else if (b < NLB + NEB + 6){              // ---- pack w_hh (K=64: 2 frags)
    int tid = (b - NLB - NEB) * 256 + threadIdx.x;
    int f = tid >> 6, l = tid & 63;
    int jt = f >> 1, kf = f & 1;
    float sc = (jt < 8) ? SC_RZ : SC_N;       // exp2-arg scale folded in
    #pragma unroll
    for (int i = 0; i < 8; ++i){
      int row = jt * 16 + (l & 15);
      int col = kf * 32 + (l >> 4) * 8 + i;
      wpk[(size_t)tid * 8 + i] = (_Float16)(sc * whh[row * HS + col]);
    }
  } else {                                    // ---- pack w_ih (K=32: 1 frag)
    int tid = (b - NLB - NEB - 6) * 256 + threadIdx.x;
    int tile = tid >> 6, l = tid & 63;
    float sc = ((tile >> 2) < 2) ? SC_RZ : SC_N;
    #pragma unroll
    for (int i = 0; i < 8; ++i){
      int row = tile * 16 + (l & 15);
      int col = (l >> 4) * 8 + i;
      wpe[(size_t)tid * 8 + i] = (_Float16)(sc * wih[row * ES + col]);
    }
  }
}

// ---------------- K2: fused scan + scatter ----------------------------------
// 16 blocks x 1024: each block redundantly scans hist[0..512] in LDS (cheap),
// then scatters its 1024 seq ids via global per-bucket atomic counters.
__global__ __launch_bounds__(1024) void k_scatter(const int* __restrict__ hist,
                                                  const int* __restrict__ len,
                                                  int* __restrict__ gcnt,
                                                  int* __restrict__ perm){
  __shared__ int buf[1024];
  __shared__ int offs[513];
  int i = threadIdx.x;
  buf[i] = (i < 513) ? hist[i] : 0;
  __syncthreads();
  for (int d = 1; d < 1024; d <<= 1){
    int v = (i >= d) ? buf[i - d] : 0;
    __syncthreads();
    buf[i] += v;
    __syncthreads();
  }
  if (i < 513) offs[i] = (i == 0) ? 0 : buf[i - 1];
  __syncthreads();
  int s = blockIdx.x * 1024 + i;
  int l = len[s];
  int pos = offs[l] + atomicAdd(&gcnt[l], 1);
  perm[pos] = s;
}

// ---------------- K3: recurrence -------------------------------------------
// R8/R12 schedule (1024 blocks, 4/CU — measured optimum; serpentine balance;
// 4-way u-split; folded exp2 scales; select-free main loop) with the per-step
// memory exposure removed: (a) all 16x512 tokens staged to LDS as u16 once
// (V=32000 < 2^16) — no in-loop global token loads, no min(); (b) TRUE
// distance-2 emb prefetch: step t consumes the emb fragment loaded at step
// t-1 and issues the load for t+2 (token from LDS) — the old code loaded and
// consumed in the same step (~200-cyc vmcnt stall every step, dead 2nd buf).
__global__ __launch_bounds__(256, 4) void k_gru(
    const int* __restrict__ x, const _Float16* __restrict__ ef,
    const _Float16* __restrict__ wpk, const _Float16* __restrict__ wpe,
    const float* __restrict__ bih, const float* __restrict__ bhh,
    const int* __restrict__ perm, const int* __restrict__ len,
    float* __restrict__ out)
{
  __shared__ __align__(16) _Float16 hb[2][16 * LDH];
  __shared__ unsigned short tok[16 * LSEQ];   // 16 KB staged tokens
  int qt   = threadIdx.x >> 6;
  int w = blockIdx.x >> 8, cq = blockIdx.x & 255;
  int rank = w * 256 + ((w & 1) ? (255 - cq) : cq);   // 0 = longest
  int grp  = 1023 - rank;                             // ascending-sorted index
  int lane = threadIdx.x & 63;
  int q = lane >> 4, c = lane & 15;
  int uu = qt*16 + c;

  v8h bfh[3][2], bfe[3];
  #pragma unroll
  for (int g = 0; g < 3; ++g){
    int tile = g*4 + qt;
    #pragma unroll
    for (int kf = 0; kf < 2; ++kf)
      bfh[g][kf] = *(const v8h*)(wpk + ((size_t)(tile*2 + kf)*64 + lane)*8);
    bfe[g] = *(const v8h*)(wpe + ((size_t)tile*64 + lane)*8);
  }

  int sq[4], ln[4];
  #pragma unroll
  for (int r = 0; r < 4; ++r){
    int s = perm[grp * 16 + q*4 + r];
    sq[r] = s;
    ln[r] = len[s];
  }
  float br  = SC_RZ * (bih[uu]      + bhh[uu]);
  float bz  = SC_RZ * (bih[HS + uu] + bhh[HS + uu]);
  float ben = SC_N  *  bih[2*HS + uu];
  float bhn = SC_N  *  bhh[2*HS + uu];
  v4f brq  = {br, br, br, br};
  v4f bzq  = {bz, bz, bz, bz};
  v4f benq = {ben, ben, ben, ben};
  v4f bhnq = {bhn, bhn, bhn, bhn};

  float h[4];
  #pragma unroll
  for (int r = 0; r < 4; ++r) h[r] = 0.f;

  for (int i = threadIdx.x; i < 16*LDH; i += 256) hb[0][i] = (_Float16)0.f;

  // stage tokens: coalesced (consecutive tid -> consecutive t of one seq);
  // rows are always full LSEQ (zero-padded), so no bounds logic needed.
  for (int j = threadIdx.x; j < 16*LSEQ; j += 256){
    int s = j >> 9, tt = j & (LSEQ-1);
    tok[j] = (unsigned short)x[(size_t)perm[grp*16 + s] * LSEQ + tt];
  }
  __syncthreads();

  int tmax = max(max(ln[0], ln[1]), max(ln[2], ln[3]));
  tmax = max(tmax, __shfl_xor(tmax, 16, 64));
  tmax = max(tmax, __shfl_xor(tmax, 32, 64));
  int tmin = min(min(ln[0], ln[1]), min(ln[2], ln[3]));
  tmin = min(tmin, __shfl_xor(tmin, 16, 64));
  tmin = min(tmin, __shfl_xor(tmin, 32, 64));

  const unsigned short* tkr = tok + c * LSEQ;   // A-row m=c token row in LDS

  v8h aec, aen;                       // emb frags: consume one, load the other
  v4f pra, prb, pza, pzb, dea, deb;   // e-partials: r, z, n (ping/pong)
  {
    int tk0 = tkr[0];
    aec = *(const v8h*)(ef + (size_t)tk0 * ES + q*8);
    pra = __builtin_amdgcn_mfma_f32_16x16x32_f16(aec, bfe[0], brq,  0,0,0);
    pza = __builtin_amdgcn_mfma_f32_16x16x32_f16(aec, bfe[1], bzq,  0,0,0);
    dea = __builtin_amdgcn_mfma_f32_16x16x32_f16(aec, bfe[2], benq, 0,0,0);
    int tk1 = tkr[1];
    aen = *(const v8h*)(ef + (size_t)tk1 * ES + q*8);   // emb for t=1
  }

  // ACONS = emb(t+1), loaded one full step ago (no vmcnt stall at its use);
  // ALOAD <- emb(t+2) issued this step (token from LDS, instant).
  #define GRU_STEP(FREEZE, ACONS, ALOAD, PRR, PRZ, DEN, PRRn, PRZn, DENn, RB, WB) \
  {                                                                            \
    int tkn = tkr[(t + 2) & (LSEQ-1)];                                         \
    v8h a0 = *(const v8h*)(&hb[RB][c*LDH + q*8]);                              \
    v8h a1 = *(const v8h*)(&hb[RB][c*LDH + 32 + q*8]);                         \
    v4f zr  = __builtin_amdgcn_mfma_f32_16x16x32_f16(a1, bfh[0][1], PRR, 0,0,0);\
    v4f Dr  = __builtin_amdgcn_mfma_f32_16x16x32_f16(a0, bfh[0][0], zr,  0,0,0);\
    v4f zz  = __builtin_amdgcn_mfma_f32_16x16x32_f16(a1, bfh[1][1], PRZ, 0,0,0);\
    v4f Dz  = __builtin_amdgcn_mfma_f32_16x16x32_f16(a0, bfh[1][0], zz,  0,0,0);\
    v4f zh  = __builtin_amdgcn_mfma_f32_16x16x32_f16(a1, bfh[2][1], bhnq,0,0,0);\
    v4f Dhn = __builtin_amdgcn_mfma_f32_16x16x32_f16(a0, bfh[2][0], zh,  0,0,0);\
    _Pragma("unroll")                                                          \
    for (int r = 0; r < 4; ++r){                                               \
      float rg   = __builtin_amdgcn_rcpf(1.f + __builtin_amdgcn_exp2f(Dr[r])); \
      float zg   = __builtin_amdgcn_rcpf(1.f + __builtin_amdgcn_exp2f(Dz[r])); \
      float te   = __builtin_amdgcn_exp2f(DEN[r] + rg * Dhn[r]);               \
      float ng   = fmaf(2.f, __builtin_amdgcn_rcpf(1.f + te), -1.f);           \
      float hnew = ng + zg * (h[r] - ng);                                      \
      h[r]       = (FREEZE && t >= ln[r]) ? h[r] : hnew;                       \
    }                                                                          \
    PRRn = __builtin_amdgcn_mfma_f32_16x16x32_f16(ACONS, bfe[0], brq,  0,0,0); \
    PRZn = __builtin_amdgcn_mfma_f32_16x16x32_f16(ACONS, bfe[1], bzq,  0,0,0); \
    DENn = __builtin_amdgcn_mfma_f32_16x16x32_f16(ACONS, bfe[2], benq, 0,0,0); \
    ALOAD = *(const v8h*)(ef + (size_t)tkn * ES + q*8);  /* emb t+2 */         \
    _Pragma("unroll")                                                          \
    for (int r = 0; r < 4; ++r)                                                \
      hb[WB][(q*4 + r)*LDH + uu] = (_Float16)h[r];                             \
    __syncthreads();                                                           \
  }

  int t = 0;
  for (; t + 1 < tmin; ){   // no-freeze main loop (t and t+1 both < all ln)
    GRU_STEP(0, aen, aec, pra, pza, dea, prb, pzb, deb, 0, 1); ++t;
    GRU_STEP(0, aec, aen, prb, pzb, deb, pra, pza, dea, 1, 0); ++t;
  }
  for (; t + 1 < tmax; ){   // tail pairs with freeze (parity preserved)
    GRU_STEP(1, aen, aec, pra, pza, dea, prb, pzb, deb, 0, 1); ++t;
    GRU_STEP(1, aec, aen, prb, pzb, deb, pra, pza, dea, 1, 0); ++t;
  }
  if (t < tmax){
    GRU_STEP(1, aen, aec, pra, pza, dea, prb, pzb, deb, 0, 1); ++t;
  }
  #undef GRU_STEP

  #pragma unroll
  for (int r = 0; r < 4; ++r)
    out[(size_t)sq[r] * HS + uu] = h[r];
}

extern "C" void kernel_launch(void* const* d_in, const int* in_sizes, int n_in,
                              void* d_out, int out_size, void* d_ws, size_t ws_size,
                              hipStream_t stream){
  const int*   x   = (const int*)  d_in[0];
  const float* emb = (const float*)d_in[1];
  const float* wih = (const float*)d_in[2];
  const float* whh = (const float*)d_in[3];
  const float* bih = (const float*)d_in[4];
  const float* bhh = (const float*)d_in[5];
  float* out = (float*)d_out;

  char* ws = (char*)d_ws;
  size_t off = 0;
  _Float16* ef  = (_Float16*)(ws + off);  off += (size_t)VOCAB * ES * sizeof(_Float16);
  _Float16* wpk = (_Float16*)(ws + off);  off += (size_t)24 * 64 * 8 * sizeof(_Float16);
  _Float16* wpe = (_Float16*)(ws + off);  off += (size_t)12 * 64 * 8 * sizeof(_Float16);
  off = (off + 255) & ~(size_t)255;
  int* len  = (int*)(ws + off);           off += (size_t)N_SEQ * sizeof(int);
  int* perm = (int*)(ws + off);           off += (size_t)N_SEQ * sizeof(int);
  int* hist = (int*)(ws + off);           off += 513 * sizeof(int);
  int* gcnt = (int*)(ws + off);           off += 513 * sizeof(int);

  hipMemsetAsync(hist, 0, 2 * 513 * sizeof(int), stream);   // hist + gcnt
  k_prep   <<<NLB + NEB + 9, 256, 0, stream>>>(x, emb, whh, wih, len, hist, ef, wpk, wpe);
  k_scatter<<<N_SEQ / 1024, 1024, 0, stream>>>(hist, len, gcnt, perm);
  k_gru    <<<N_SEQ / 16,    256, 0, stream>>>(x, ef, wpk, wpe, bih, bhh, perm, len, out);
}